// Round 11
// baseline (220.111 us; speedup 1.0000x reference)
//
#include <hip/hip_runtime.h>
#include <math.h>

#define NEGS 0.2f
#define EPSF 1e-5f

typedef short s16x8 __attribute__((ext_vector_type(8)));
typedef float f32x4 __attribute__((ext_vector_type(4)));

__device__ __forceinline__ float b2f(unsigned short u) {
  union { unsigned int i; float f; } v; v.i = ((unsigned int)u) << 16; return v.f;
}
__device__ __forceinline__ unsigned short f2b(float f) {
  union { float f; unsigned int i; } v; v.f = f;
  unsigned int x = v.i;
  return (unsigned short)((x + 0x7fffu + ((x >> 16) & 1u)) >> 16);
}
__device__ __forceinline__ float eluf(float x) { return x > 0.f ? x : expm1f(x); }

__device__ __forceinline__ float block_reduce1024(float v, float* red) {
  #pragma unroll
  for (int o = 32; o > 0; o >>= 1) v += __shfl_down(v, o);
  __syncthreads();
  if ((threadIdx.x & 63) == 0) red[threadIdx.x >> 6] = v;
  __syncthreads();
  float s = 0.f;
  #pragma unroll
  for (int i = 0; i < 16; ++i) s += red[i];
  return s;
}

// ---- pre-pass: inp->Xb transpose+cvt (blocks 0..511); W0b/W1b cvt (512..575);
// ---- attention vectors vl/vr (block 576): vl1[h][k] = sum_d W1[(h*64+d)*256+k]*al1[h*64+d]
__global__ __launch_bounds__(256) void k_pre(
    const float* __restrict__ inp, const float* __restrict__ W0,
    const float* __restrict__ W1, const float* __restrict__ al0,
    const float* __restrict__ ar0, const float* __restrict__ al1,
    const float* __restrict__ ar1, unsigned short* __restrict__ Xb,
    unsigned short* __restrict__ W0b, unsigned short* __restrict__ W1b,
    float* __restrict__ vl0g, float* __restrict__ vr0g,
    float* __restrict__ vl1g, float* __restrict__ vr1g)
{
  const int tid = threadIdx.x;
  if (blockIdx.x == 576) {
    float accl1[4] = {0,0,0,0}, accr1[4] = {0,0,0,0};
    #pragma unroll
    for (int h = 0; h < 4; ++h)
      for (int d = 0; d < 64; ++d) {
        float w = W1[(size_t)(h*64 + d)*256 + tid];
        accl1[h] = fmaf(w, al1[h*64 + d], accl1[h]);
        accr1[h] = fmaf(w, ar1[h*64 + d], accr1[h]);
      }
    #pragma unroll
    for (int h = 0; h < 4; ++h) { vl1g[h*256 + tid] = accl1[h]; vr1g[h*256 + tid] = accr1[h]; }
    if (tid < 64) {
      float accl0[4] = {0,0,0,0}, accr0[4] = {0,0,0,0};
      for (int h = 0; h < 4; ++h)
        for (int d = 0; d < 64; ++d) {
          float w = W0[(h*64 + d)*64 + tid];
          accl0[h] = fmaf(w, al0[h*64 + d], accl0[h]);
          accr0[h] = fmaf(w, ar0[h*64 + d], accr0[h]);
        }
      for (int h = 0; h < 4; ++h) { vl0g[h*64 + tid] = accl0[h]; vr0g[h*64 + tid] = accr0[h]; }
    }
    return;
  }
  if (blockIdx.x >= 512) {
    const int j = (blockIdx.x - 512) * 256 + tid;   // [0,16384)
    W0b[j] = f2b(W0[j]);
    float4 w4 = *(const float4*)&W1[j*4];
    ushort4 o4; o4.x=f2b(w4.x); o4.y=f2b(w4.y); o4.z=f2b(w4.z); o4.w=f2b(w4.w);
    *(ushort4*)&W1b[j*4] = o4;
    return;
  }
  __shared__ float L[64][65];
  const int blk = blockIdx.x;
  const int n0 = (blk & 15) * 64;
  const int t  = (blk >> 4) & 7;
  const int b  = blk >> 7;
  const int nn = tid & 63, ch0 = tid >> 6;
  #pragma unroll
  for (int ch = ch0; ch < 64; ch += 4)
    L[ch][nn] = inp[((size_t)(b*64 + ch)*8 + t)*1024 + n0 + nn];
  __syncthreads();
  const int r = tid >> 2, ck = tid & 3;
  s16x8 o0, o1;
  #pragma unroll
  for (int i = 0; i < 8; ++i) o0[i] = (short)f2b(L[ck*16 + i][r]);
  #pragma unroll
  for (int i = 0; i < 8; ++i) o1[i] = (short)f2b(L[ck*16 + 8 + i][r]);
  const int row = (n0 + r)*32 + b*8 + t;
  *(s16x8*)&Xb[(size_t)row*64 + ck*16]     = o0;
  *(s16x8*)&Xb[(size_t)row*64 + ck*16 + 8] = o1;
}

// ---- layer 0 full: gather x (128B rows), attention via vl0/vr0, per-head agg,
// ---- MFMA @ W0^T, elu -> h1; epilogue computes el1/er1 = h1 . vl1/vr1.
__global__ __launch_bounds__(256) void k_l0(
    const unsigned short* __restrict__ Xb, const int* __restrict__ src,
    const unsigned short* __restrict__ W0b, const float* __restrict__ vl0g,
    const float* __restrict__ vr0g, const float* __restrict__ vl1g,
    const float* __restrict__ vr1g, unsigned short* __restrict__ h1b,
    float* __restrict__ el1, float* __restrict__ er1)
{
  __shared__ int   ssm[32][8];
  __shared__ __align__(16) float vl0s[4][64], vr0s[4][64];
  __shared__ __align__(16) float vl1s[4][256], vr1s[4][256];
  __shared__ float er0s[32][4];
  __shared__ float el0s[32][8][4];
  __shared__ float a_lds[32][33];
  __shared__ __align__(16) unsigned short x_lds[32][8][72];  // reused as h1 bounce
  __shared__ __align__(16) unsigned short At[4][32][72];     // per-head g0 tiles
  __shared__ float elpart[4][32][4], erpart[4][32][4];
  const int tid = threadIdx.x;
  const int g     = blockIdx.x & 7;
  const int bt    = g*4 + ((blockIdx.x >> 3) & 3);
  const int nBase = (blockIdx.x >> 5) * 32;

  // P0: stage src + vectors
  ((int*)ssm)[tid] = src[nBase*8 + tid];
  ((float4*)vl1s)[tid] = ((const float4*)vl1g)[tid];
  ((float4*)vr1s)[tid] = ((const float4*)vr1g)[tid];
  if (tid < 64) {
    ((float4*)vl0s)[tid] = ((const float4*)vl0g)[tid];
    ((float4*)vr0s)[tid] = ((const float4*)vr0g)[tid];
  }
  __syncthreads();

  // P1: thread (nl, j): gather neighbor row (128B), el0 partials; own-row er0 chunk
  {
    const int nl = tid >> 3, j = tid & 7;
    const unsigned short* xp = Xb + (size_t)(ssm[nl][j]*32 + bt)*64;
    s16x8 xr[8];
    #pragma unroll
    for (int i = 0; i < 8; ++i) xr[i] = *(const s16x8*)&xp[i*8];
    s16x8 xo = *(const s16x8*)&Xb[(size_t)((nBase + nl)*32 + bt)*64 + j*8];
    asm volatile("" ::: "memory");
    #pragma unroll
    for (int h = 0; h < 4; ++h) {
      float s = 0.f;
      #pragma unroll
      for (int i = 0; i < 8; ++i) {
        f32x4 va = *(const f32x4*)&vl0s[h][i*8];
        f32x4 vb = *(const f32x4*)&vl0s[h][i*8 + 4];
        s = fmaf(b2f((unsigned short)xr[i][0]), va[0], s);
        s = fmaf(b2f((unsigned short)xr[i][1]), va[1], s);
        s = fmaf(b2f((unsigned short)xr[i][2]), va[2], s);
        s = fmaf(b2f((unsigned short)xr[i][3]), va[3], s);
        s = fmaf(b2f((unsigned short)xr[i][4]), vb[0], s);
        s = fmaf(b2f((unsigned short)xr[i][5]), vb[1], s);
        s = fmaf(b2f((unsigned short)xr[i][6]), vb[2], s);
        s = fmaf(b2f((unsigned short)xr[i][7]), vb[3], s);
      }
      el0s[nl][j][h] = s;
    }
    // own-row er0 partial over ch [j*8, j*8+8)
    float erp[4];
    #pragma unroll
    for (int h = 0; h < 4; ++h) {
      f32x4 va = *(const f32x4*)&vr0s[h][j*8];
      f32x4 vb = *(const f32x4*)&vr0s[h][j*8 + 4];
      float s = b2f((unsigned short)xo[0])*va[0] + b2f((unsigned short)xo[1])*va[1]
              + b2f((unsigned short)xo[2])*va[2] + b2f((unsigned short)xo[3])*va[3]
              + b2f((unsigned short)xo[4])*vb[0] + b2f((unsigned short)xo[5])*vb[1]
              + b2f((unsigned short)xo[6])*vb[2] + b2f((unsigned short)xo[7])*vb[3];
      erp[h] = s;
    }
    #pragma unroll
    for (int o = 1; o < 8; o <<= 1)
      #pragma unroll
      for (int h = 0; h < 4; ++h) erp[h] += __shfl_xor(erp[h], o);
    if (j == 0)
      #pragma unroll
      for (int h = 0; h < 4; ++h) er0s[nl][h] = erp[h];
    #pragma unroll
    for (int i = 0; i < 8; ++i) *(s16x8*)&x_lds[nl][j][i*8] = xr[i];
  }
  __syncthreads();

  // P2: softmax weights
  if (tid < 128) {
    const int nl = tid >> 2, h = tid & 3;
    const float erv = er0s[nl][h];
    float e[8]; float mx = -1e30f;
    #pragma unroll
    for (int j = 0; j < 8; ++j) {
      float v = el0s[nl][j][h] + erv;
      v = v >= 0.f ? v : NEGS * v;
      e[j] = v; mx = fmaxf(mx, v);
    }
    float den = 0.f;
    #pragma unroll
    for (int j = 0; j < 8; ++j) { e[j] = __expf(e[j] - mx); den += e[j]; }
    const float inv = 1.f / den;
    #pragma unroll
    for (int j = 0; j < 8; ++j) a_lds[nl][j*4 + h] = e[j] * inv;
  }
  __syncthreads();

  // P3: per-head weighted sum -> At[h][nl][ch]
  {
    const int nl = tid >> 3, ci = tid & 7;
    s16x8 xv[8];
    #pragma unroll
    for (int j = 0; j < 8; ++j) xv[j] = *(const s16x8*)&x_lds[nl][j][ci*8];
    #pragma unroll
    for (int h = 0; h < 4; ++h) {
      float acc8[8] = {0,0,0,0,0,0,0,0};
      #pragma unroll
      for (int j = 0; j < 8; ++j) {
        const float wa = a_lds[nl][j*4 + h];
        #pragma unroll
        for (int e = 0; e < 8; ++e)
          acc8[e] = fmaf(wa, b2f((unsigned short)xv[j][e]), acc8[e]);
      }
      s16x8 o;
      #pragma unroll
      for (int e = 0; e < 8; ++e) o[e] = (short)f2b(acc8[e]);
      *(s16x8*)&At[h][nl][ci*8] = o;
    }
  }
  __syncthreads();

  // P4: MFMA per head: wave w uses At[w] (32x64) @ W0b cols [64w,64w+64)
  const int w    = tid >> 6;
  const int lane = tid & 63;
  const int n16  = lane & 15;
  const int q    = lane >> 4;
  f32x4 acc[2][4];
  #pragma unroll
  for (int rt = 0; rt < 2; ++rt)
    #pragma unroll
    for (int ct = 0; ct < 4; ++ct) acc[rt][ct] = (f32x4){0.f,0.f,0.f,0.f};
  #pragma unroll
  for (int kc = 0; kc < 2; ++kc) {
    s16x8 af[2], bfr[4];
    #pragma unroll
    for (int rt = 0; rt < 2; ++rt)
      af[rt] = *(const s16x8*)&At[w][rt*16 + n16][kc*32 + q*8];
    #pragma unroll
    for (int ct = 0; ct < 4; ++ct)
      bfr[ct] = *(const s16x8*)&W0b[(size_t)((w*4 + ct)*16 + n16)*64 + kc*32 + q*8];
    #pragma unroll
    for (int rt = 0; rt < 2; ++rt)
      #pragma unroll
      for (int ct = 0; ct < 4; ++ct)
        acc[rt][ct] = __builtin_amdgcn_mfma_f32_16x16x32_bf16(af[rt], bfr[ct], acc[rt][ct], 0, 0, 0);
  }

  // P5: elu -> h1; el1/er1 partials; bounce h1 into x_lds region
  {
    float vl1v[4][4], vr1v[4][4];
    #pragma unroll
    for (int h = 0; h < 4; ++h)
      #pragma unroll
      for (int ct = 0; ct < 4; ++ct) {
        vl1v[h][ct] = vl1s[h][w*64 + ct*16 + n16];
        vr1v[h][ct] = vr1s[h][w*64 + ct*16 + n16];
      }
    unsigned short* Hb = &x_lds[0][0][0];   // [32][256]
    #pragma unroll
    for (int rt = 0; rt < 2; ++rt) {
      #pragma unroll
      for (int reg = 0; reg < 4; ++reg) {
        const int row = rt*16 + q*4 + reg;
        float hv[4];
        #pragma unroll
        for (int ct = 0; ct < 4; ++ct) hv[ct] = eluf(acc[rt][ct][reg]);
        float ep[4], rp[4];
        #pragma unroll
        for (int h = 0; h < 4; ++h) {
          ep[h] = hv[0]*vl1v[h][0] + hv[1]*vl1v[h][1] + hv[2]*vl1v[h][2] + hv[3]*vl1v[h][3];
          rp[h] = hv[0]*vr1v[h][0] + hv[1]*vr1v[h][1] + hv[2]*vr1v[h][2] + hv[3]*vr1v[h][3];
        }
        #pragma unroll
        for (int o = 1; o < 16; o <<= 1)
          #pragma unroll
          for (int h = 0; h < 4; ++h) { ep[h] += __shfl_xor(ep[h], o); rp[h] += __shfl_xor(rp[h], o); }
        if (n16 == 0)
          #pragma unroll
          for (int h = 0; h < 4; ++h) { elpart[w][row][h] = ep[h]; erpart[w][row][h] = rp[h]; }
        #pragma unroll
        for (int ct = 0; ct < 4; ++ct)
          Hb[row*256 + w*64 + ct*16 + n16] = f2b(hv[ct]);
      }
    }
  }
  __syncthreads();

  // P6: coalesced h1b write + el1/er1 reduce
  {
    const unsigned short* Hb = &x_lds[0][0][0];
    #pragma unroll
    for (int i = 0; i < 4; ++i) {
      int u = tid + i*256;
      int row = u >> 5, off = (u & 31) * 8;
      *(s16x8*)&h1b[(size_t)((nBase + row)*32 + bt)*256 + off] = *(const s16x8*)&Hb[row*256 + off];
    }
    if (tid < 128) {
      const int row = tid >> 2, h = tid & 3;
      float se = 0.f, sr = 0.f;
      #pragma unroll
      for (int ww = 0; ww < 4; ++ww) { se += elpart[ww][row][h]; sr += erpart[ww][row][h]; }
      const int r = (nBase + row)*32 + bt;
      el1[r*4 + h] = se;
      er1[r*4 + h] = sr;
    }
  }
}

// ---- layer 1 + proj: gather h1, agg -> g1, MFMA g1@W1^T, +h1 residual, elu -> h2, proj
__global__ __launch_bounds__(256, 3) void k_l1(
    const unsigned short* __restrict__ h1b, const float* __restrict__ el,
    const float* __restrict__ er, const int* __restrict__ src,
    const unsigned short* __restrict__ W1b, const float* __restrict__ W2,
    const float* __restrict__ Wres2, float* __restrict__ feat2, float* __restrict__ res2)
{
  __shared__ float wsm[32][8][4];
  __shared__ int   ssm[32][8];
  __shared__ __align__(16) float Wp[8][256];
  __shared__ __align__(16) unsigned short At[32][264];
  __shared__ __align__(16) unsigned short own[32][264];
  __shared__ float pp[4][32][8];
  const int tid = threadIdx.x;
  const int g     = blockIdx.x & 7;
  const int bt    = g*4 + ((blockIdx.x >> 3) & 3);
  const int nBase = (blockIdx.x >> 5) * 32;
  ((int*)ssm)[tid] = src[nBase*8 + tid];
  for (int j2 = tid; j2 < 2048; j2 += 256) {
    int o = j2 >> 8, k = j2 & 255;
    Wp[o][k] = (o < 4) ? W2[o*256 + k] : Wres2[(o-4)*256 + k];
  }
  __syncthreads();
  if (tid < 128) {
    const int nl = tid >> 2, h = tid & 3;
    const int rn = (nBase + nl)*32 + bt;
    const float erv = er[rn*4 + h];
    float e[8]; float mx = -1e30f;
    #pragma unroll
    for (int j = 0; j < 8; ++j) {
      float v = el[(ssm[nl][j]*32 + bt)*4 + h] + erv;
      v = v >= 0.f ? v : NEGS * v;
      e[j] = v; mx = fmaxf(mx, v);
    }
    float den = 0.f;
    #pragma unroll
    for (int j = 0; j < 8; ++j) { e[j] = __expf(e[j] - mx); den += e[j]; }
    const float inv = 1.f / den;
    #pragma unroll
    for (int j = 0; j < 8; ++j) wsm[nl][j][h] = e[j] * inv;
  }
  __syncthreads();
  // PB: gather + weighted sum -> At (g1, bf16); also stage own rows
  {
    const int hw2 = tid >> 5, l5 = tid & 31;
    const int c0 = l5 * 8, hh = l5 >> 3;
    #pragma unroll
    for (int p2 = 0; p2 < 2; ++p2) {
      const int nlA = p2*16 + hw2, nlB = nlA + 8;
      s16x8 vA[8], vB[8];
      #pragma unroll
      for (int j = 0; j < 8; ++j) {
        vA[j] = *(const s16x8*)&h1b[(size_t)(ssm[nlA][j]*32 + bt)*256 + c0];
        vB[j] = *(const s16x8*)&h1b[(size_t)(ssm[nlB][j]*32 + bt)*256 + c0];
      }
      asm volatile("" ::: "memory");
      float aA[8] = {0,0,0,0,0,0,0,0}, aB[8] = {0,0,0,0,0,0,0,0};
      #pragma unroll
      for (int j = 0; j < 8; ++j) {
        const float wA = wsm[nlA][j][hh], wB = wsm[nlB][j][hh];
        #pragma unroll
        for (int i = 0; i < 8; ++i) {
          aA[i] = fmaf(wA, b2f((unsigned short)vA[j][i]), aA[i]);
          aB[i] = fmaf(wB, b2f((unsigned short)vB[j][i]), aB[i]);
        }
      }
      s16x8 oA, oB;
      #pragma unroll
      for (int i = 0; i < 8; ++i) { oA[i] = (short)f2b(aA[i]); oB[i] = (short)f2b(aB[i]); }
      *(s16x8*)&At[nlA][c0] = oA;
      *(s16x8*)&At[nlB][c0] = oB;
    }
    #pragma unroll
    for (int i = 0; i < 4; ++i) {
      int u = tid + i*256;
      int row = u >> 5, off = (u & 31) * 8;
      *(s16x8*)&own[row][off] = *(const s16x8*)&h1b[(size_t)((nBase + row)*32 + bt)*256 + off];
    }
  }
  __syncthreads();
  // PC: MFMA g1 @ W1^T (32x256x256)
  const int w    = tid >> 6;
  const int lane = tid & 63;
  const int n16  = lane & 15;
  const int q    = lane >> 4;
  f32x4 acc[2][4];
  #pragma unroll
  for (int rt = 0; rt < 2; ++rt)
    #pragma unroll
    for (int ct = 0; ct < 4; ++ct) acc[rt][ct] = (f32x4){0.f,0.f,0.f,0.f};
  #pragma unroll
  for (int kc = 0; kc < 8; ++kc) {
    s16x8 af[2], bfr[4];
    #pragma unroll
    for (int rt = 0; rt < 2; ++rt)
      af[rt] = *(const s16x8*)&At[rt*16 + n16][kc*32 + q*8];
    #pragma unroll
    for (int ct = 0; ct < 4; ++ct)
      bfr[ct] = *(const s16x8*)&W1b[(size_t)((w*4 + ct)*16 + n16)*256 + kc*32 + q*8];
    #pragma unroll
    for (int rt = 0; rt < 2; ++rt)
      #pragma unroll
      for (int ct = 0; ct < 4; ++ct)
        acc[rt][ct] = __builtin_amdgcn_mfma_f32_16x16x32_bf16(af[rt], bfr[ct], acc[rt][ct], 0, 0, 0);
  }
  // PD: h2 = elu(acc + own); proj partials
  {
    float wpv[8][4];
    #pragma unroll
    for (int o = 0; o < 8; ++o)
      #pragma unroll
      for (int ct = 0; ct < 4; ++ct) wpv[o][ct] = Wp[o][w*64 + ct*16 + n16];
    #pragma unroll
    for (int rt = 0; rt < 2; ++rt) {
      #pragma unroll
      for (int reg = 0; reg < 4; ++reg) {
        const int row = rt*16 + q*4 + reg;
        float h2[4];
        #pragma unroll
        for (int ct = 0; ct < 4; ++ct) {
          float v = acc[rt][ct][reg] + b2f(own[row][w*64 + ct*16 + n16]);
          h2[ct] = eluf(v);
        }
        float pf[8];
        #pragma unroll
        for (int o = 0; o < 8; ++o)
          pf[o] = h2[0]*wpv[o][0] + h2[1]*wpv[o][1] + h2[2]*wpv[o][2] + h2[3]*wpv[o][3];
        #pragma unroll
        for (int of = 1; of < 16; of <<= 1)
          #pragma unroll
          for (int o = 0; o < 8; ++o) pf[o] += __shfl_xor(pf[o], of);
        if (n16 == 0)
          #pragma unroll
          for (int o = 0; o < 8; ++o) pp[w][row][o] = pf[o];
      }
    }
  }
  __syncthreads();
  // PE: reduce across waves, write feat2/res2
  {
    const int row = tid >> 3, o = tid & 7;
    float s = pp[0][row][o] + pp[1][row][o] + pp[2][row][o] + pp[3][row][o];
    const int rn = (nBase + row)*32 + bt;
    if (o < 4) feat2[rn*4 + o] = s;
    else       res2[rn*4 + (o-4)] = s;
  }
}

// ---------------- layer 2 aggregate + tc1 einsum -> x1[b][o][n] ----------------
__global__ __launch_bounds__(128) void k_agg2(
    const float* __restrict__ feat2, const float* __restrict__ res2,
    const int* __restrict__ src, const float* __restrict__ al2,
    const float* __restrict__ ar2, const float* __restrict__ tc1w,
    const float* __restrict__ tc1b, float* __restrict__ x1)
{
  __shared__ float os[4][8][4];   // [b][t][h]
  const int n = blockIdx.x;
  const int tid = threadIdx.x;
  const int b = tid >> 5, t = (tid >> 2) & 7, h = tid & 3;
  const int rn = n*32 + b*8 + t;
  const float av = al2[h], rv = ar2[h];
  const float erv = feat2[rn*4 + h] * rv;
  float f[8], e[8]; float m = -1e30f;
  #pragma unroll
  for (int j = 0; j < 8; ++j) {
    int s_ = src[n*8 + j];
    f[j] = feat2[(s_*32 + b*8 + t)*4 + h];
    float v = f[j]*av + erv;
    v = v >= 0.f ? v : NEGS * v;
    e[j] = v; m = fmaxf(m, v);
  }
  float den = 0.f, num = 0.f;
  #pragma unroll
  for (int j = 0; j < 8; ++j) { float ex = __expf(e[j]-m); den += ex; num = fmaf(ex, f[j], num); }
  os[b][t][h] = num/den + res2[rn*4 + h];
  __syncthreads();
  if (tid < 16) {
    int b2 = tid >> 2, o2 = tid & 3;
    float acc = tc1b[o2];
    #pragma unroll
    for (int hh = 0; hh < 4; ++hh)
      #pragma unroll
      for (int tt = 0; tt < 8; ++tt)
        acc = fmaf(tc1w[(o2*4 + hh)*8 + tt], os[b2][tt][hh], acc);
    x1[(b2*4 + o2)*1024 + n] = acc;
  }
}

// ---------------- head: LN1 -> tc2 -> LN2 -> conv -> out (B x 7) ----------------
__global__ __launch_bounds__(1024) void k_final(
    const float* __restrict__ x1, const float* __restrict__ ln1g,
    const float* __restrict__ ln1b, const float* __restrict__ tc2w,
    const float* __restrict__ tc2b, const float* __restrict__ ln2g,
    const float* __restrict__ ln2b, const float* __restrict__ fcw,
    const float* __restrict__ fcb, float* __restrict__ out)
{
  __shared__ float red[16];
  __shared__ float x2s[1024];
  const int b = blockIdx.x;
  const int tid = threadIdx.x;
  float s = 0.f, q = 0.f;
  for (int j = tid; j < 4096; j += 1024) {
    float v = x1[b*4096 + j];
    s += v; q += v*v;
  }
  float S = block_reduce1024(s, red);
  float Q = block_reduce1024(q, red);
  float mu  = S * (1.f/4096.f);
  float var = Q * (1.f/4096.f) - mu*mu;
  float inv = rsqrtf(var + EPSF);
  float tb = tc2b[0];
  const int nn = tid;
  float acc = tb;
  #pragma unroll
  for (int h = 0; h < 4; ++h) {
    float z = (x1[b*4096 + h*1024 + nn] - mu) * inv * ln1g[nn*4 + h] + ln1b[nn*4 + h];
    acc = fmaf(tc2w[h], z, acc);
  }
  float S2 = block_reduce1024(acc, red);
  float Q2 = block_reduce1024(acc*acc, red);
  float mu2  = S2 * (1.f/1024.f);
  float inv2 = rsqrtf(Q2 * (1.f/1024.f) - mu2*mu2 + EPSF);
  x2s[nn] = (acc - mu2) * inv2 * ln2g[nn] + ln2b[nn];
  __syncthreads();
  for (int c = 0; c < 7; ++c) {
    float p = (tid < 1018) ? x2s[c + tid] * fcw[tid] : 0.f;
    float P = block_reduce1024(p, red);
    if (tid == 0) out[b*7 + c] = P + fcb[0];
  }
}

extern "C" void kernel_launch(void* const* d_in, const int* in_sizes, int n_in,
                              void* d_out, int out_size, void* d_ws, size_t ws_size,
                              hipStream_t stream)
{
  const float* inp  = (const float*)d_in[0];
  const int*   src  = (const int*)  d_in[1];
  const float* W0   = (const float*)d_in[3];
  const float* al0  = (const float*)d_in[4];
  const float* ar0  = (const float*)d_in[5];
  const float* W1   = (const float*)d_in[6];
  const float* al1  = (const float*)d_in[7];
  const float* ar1  = (const float*)d_in[8];
  const float* W2   = (const float*)d_in[9];
  const float* al2  = (const float*)d_in[10];
  const float* ar2  = (const float*)d_in[11];
  const float* Wr2  = (const float*)d_in[12];
  const float* tc1w = (const float*)d_in[13];
  const float* tc1b = (const float*)d_in[14];
  const float* ln1g = (const float*)d_in[15];
  const float* ln1b = (const float*)d_in[16];
  const float* tc2w = (const float*)d_in[17];
  const float* tc2b = (const float*)d_in[18];
  const float* ln2g = (const float*)d_in[19];
  const float* ln2b = (const float*)d_in[20];
  const float* fcw  = (const float*)d_in[21];
  const float* fcb  = (const float*)d_in[22];
  float* out = (float*)d_out;

  unsigned short* Xb   = (unsigned short*)d_ws;   // 2,097,152
  unsigned short* W0b  = Xb  + 2097152;           // 16,384
  unsigned short* W1b  = W0b + 16384;             // 65,536
  unsigned short* h1b  = W1b + 65536;             // 8,388,608
  float* vl0g  = (float*)(h1b + 8388608);         // 256
  float* vr0g  = vl0g + 256;
  float* vl1g  = vr0g + 256;                      // 1024
  float* vr1g  = vl1g + 1024;
  float* el1   = vr1g + 1024;                     // 131,072
  float* er1   = el1 + 131072;
  float* feat2 = er1 + 131072;
  float* res2  = feat2 + 131072;
  float* x1    = res2 + 131072;                   // 16,384

  k_pre<<<dim3(577), dim3(256), 0, stream>>>(inp, W0, W1, al0, ar0, al1, ar1,
                                             Xb, W0b, W1b, vl0g, vr0g, vl1g, vr1g);
  k_l0<<<dim3(1024), dim3(256), 0, stream>>>(Xb, src, W0b, vl0g, vr0g, vl1g, vr1g,
                                             h1b, el1, er1);
  k_l1<<<dim3(1024), dim3(256), 0, stream>>>(h1b, el1, er1, src, W1b, W2, Wr2,
                                             feat2, res2);
  k_agg2<<<dim3(1024), dim3(128), 0, stream>>>(feat2, res2, src, al2, ar2, tc1w, tc1b, x1);
  k_final<<<dim3(4), dim3(1024), 0, stream>>>(x1, ln1g, ln1b, tc2w, tc2b, ln2g, ln2b, fcw, fcb, out);
}

// Round 12
// 195.810 us; speedup vs baseline: 1.1241x; 1.1241x over previous
//
#include <hip/hip_runtime.h>
#include <math.h>

#define NEGS 0.2f
#define EPSF 1e-5f

typedef short s16x8 __attribute__((ext_vector_type(8)));
typedef float f32x4 __attribute__((ext_vector_type(4)));

__device__ __forceinline__ float b2f(unsigned short u) {
  union { unsigned int i; float f; } v; v.i = ((unsigned int)u) << 16; return v.f;
}
__device__ __forceinline__ unsigned short f2b(float f) {
  union { float f; unsigned int i; } v; v.f = f;
  unsigned int x = v.i;
  return (unsigned short)((x + 0x7fffu + ((x >> 16) & 1u)) >> 16);
}
__device__ __forceinline__ float eluf(float x) { return x > 0.f ? x : expm1f(x); }

__device__ __forceinline__ float block_reduce1024(float v, float* red) {
  #pragma unroll
  for (int o = 32; o > 0; o >>= 1) v += __shfl_down(v, o);
  __syncthreads();
  if ((threadIdx.x & 63) == 0) red[threadIdx.x >> 6] = v;
  __syncthreads();
  float s = 0.f;
  #pragma unroll
  for (int i = 0; i < 16; ++i) s += red[i];
  return s;
}

// ---- pre0: W0/W1 -> bf16 (blocks 0..63); attention vectors vl/vr (block 64) ----
__global__ __launch_bounds__(256) void k_pre0(
    const float* __restrict__ W0, const float* __restrict__ W1,
    const float* __restrict__ al0, const float* __restrict__ ar0,
    const float* __restrict__ al1, const float* __restrict__ ar1,
    unsigned short* __restrict__ W0b, unsigned short* __restrict__ W1b,
    float* __restrict__ vl0g, float* __restrict__ vr0g,
    float* __restrict__ vl1g, float* __restrict__ vr1g)
{
  const int tid = threadIdx.x;
  if (blockIdx.x == 64) {
    float accl1[4] = {0,0,0,0}, accr1[4] = {0,0,0,0};
    #pragma unroll
    for (int h = 0; h < 4; ++h)
      for (int d = 0; d < 64; ++d) {
        float w = W1[(size_t)(h*64 + d)*256 + tid];
        accl1[h] = fmaf(w, al1[h*64 + d], accl1[h]);
        accr1[h] = fmaf(w, ar1[h*64 + d], accr1[h]);
      }
    #pragma unroll
    for (int h = 0; h < 4; ++h) { vl1g[h*256 + tid] = accl1[h]; vr1g[h*256 + tid] = accr1[h]; }
    if (tid < 64) {
      float accl0[4] = {0,0,0,0}, accr0[4] = {0,0,0,0};
      for (int h = 0; h < 4; ++h)
        for (int d = 0; d < 64; ++d) {
          float w = W0[(h*64 + d)*64 + tid];
          accl0[h] = fmaf(w, al0[h*64 + d], accl0[h]);
          accr0[h] = fmaf(w, ar0[h*64 + d], accr0[h]);
        }
      for (int h = 0; h < 4; ++h) { vl0g[h*64 + tid] = accl0[h]; vr0g[h*64 + tid] = accr0[h]; }
    }
    return;
  }
  const int j = blockIdx.x * 256 + tid;   // [0,16384)
  W0b[j] = f2b(W0[j]);
  float4 w4 = *(const float4*)&W1[j*4];
  ushort4 o4; o4.x=f2b(w4.x); o4.y=f2b(w4.y); o4.z=f2b(w4.z); o4.w=f2b(w4.w);
  *(ushort4*)&W1b[j*4] = o4;
}

// ---- pre1: inp -> Xb transpose+cvt, plus el0/er0 per row (once) ----
__global__ __launch_bounds__(256) void k_pre1(
    const float* __restrict__ inp, const float* __restrict__ vl0g,
    const float* __restrict__ vr0g, unsigned short* __restrict__ Xb,
    float* __restrict__ el0g, float* __restrict__ er0g)
{
  __shared__ float L[64][65];
  __shared__ float vl0s[256], vr0s[256];
  const int tid = threadIdx.x;
  const int blk = blockIdx.x;
  const int n0 = (blk & 15) * 64;
  const int t  = (blk >> 4) & 7;
  const int b  = blk >> 7;
  vl0s[tid] = vl0g[tid];
  vr0s[tid] = vr0g[tid];
  const int nn = tid & 63, ch0 = tid >> 6;
  #pragma unroll
  for (int ch = ch0; ch < 64; ch += 4)
    L[ch][nn] = inp[((size_t)(b*64 + ch)*8 + t)*1024 + n0 + nn];
  __syncthreads();
  {
    const int r = tid >> 2, ck = tid & 3;
    s16x8 o0, o1;
    #pragma unroll
    for (int i = 0; i < 8; ++i) o0[i] = (short)f2b(L[ck*16 + i][r]);
    #pragma unroll
    for (int i = 0; i < 8; ++i) o1[i] = (short)f2b(L[ck*16 + 8 + i][r]);
    const int row = (n0 + r)*32 + b*8 + t;
    *(s16x8*)&Xb[(size_t)row*64 + ck*16]     = o0;
    *(s16x8*)&Xb[(size_t)row*64 + ck*16 + 8] = o1;
  }
  {
    const int h = tid >> 6;     // wave = head
    float sl = 0.f, sr = 0.f;
    #pragma unroll
    for (int c = 0; c < 64; ++c) {
      float xv = L[c][nn];
      sl = fmaf(xv, vl0s[h*64 + c], sl);
      sr = fmaf(xv, vr0s[h*64 + c], sr);
    }
    const int row = (n0 + nn)*32 + b*8 + t;
    el0g[row*4 + h] = sl;
    er0g[row*4 + h] = sr;
  }
}

// ---- layer 0: softmax(el0/er0) -> per-head agg of x -> MFMA @ W0^T -> elu -> h1,
// ---- epilogue el1/er1 = h1 . vl1/vr1. block = (bt, 32 nodes), XCD-swizzled.
__global__ __launch_bounds__(256, 4) void k_l0(
    const unsigned short* __restrict__ Xb, const int* __restrict__ src,
    const unsigned short* __restrict__ W0b, const float* __restrict__ el0g,
    const float* __restrict__ er0g, const float* __restrict__ vl1g,
    const float* __restrict__ vr1g, unsigned short* __restrict__ h1b,
    float* __restrict__ el1, float* __restrict__ er1)
{
  __shared__ int ssm[32][8];
  __shared__ float a_lds[32][33];
  __shared__ __align__(16) unsigned short At[4][32][72];   // 18432 B; reused as h1 bounce
  __shared__ float elpart[4][32][4], erpart[4][32][4];
  const int tid = threadIdx.x;
  const int g     = blockIdx.x & 7;
  const int bt    = g*4 + ((blockIdx.x >> 3) & 3);
  const int nBase = (blockIdx.x >> 5) * 32;
  ((int*)ssm)[tid] = src[nBase*8 + tid];
  __syncthreads();
  // P1: softmax weights (128 threads)
  if (tid < 128) {
    const int nl = tid >> 2, h = tid & 3;
    const int rn = (nBase + nl)*32 + bt;
    const float erv = er0g[rn*4 + h];
    float e[8]; float mx = -1e30f;
    #pragma unroll
    for (int j = 0; j < 8; ++j) {
      float v = el0g[(ssm[nl][j]*32 + bt)*4 + h] + erv;
      v = v >= 0.f ? v : NEGS * v;
      e[j] = v; mx = fmaxf(mx, v);
    }
    float den = 0.f;
    #pragma unroll
    for (int j = 0; j < 8; ++j) { e[j] = __expf(e[j] - mx); den += e[j]; }
    const float inv = 1.f / den;
    #pragma unroll
    for (int j = 0; j < 8; ++j) a_lds[nl][j*4 + h] = e[j] * inv;
  }
  __syncthreads();
  // P2: per-head weighted x-aggregate (thread = (nl, ci)); gathers from L2-resident Xb
  {
    const int nl = tid >> 3, ci = tid & 7;
    s16x8 xv[8];
    #pragma unroll
    for (int j = 0; j < 8; ++j)
      xv[j] = *(const s16x8*)&Xb[(size_t)(ssm[nl][j]*32 + bt)*64 + ci*8];
    asm volatile("" ::: "memory");
    float acc4[4][8];
    #pragma unroll
    for (int h = 0; h < 4; ++h)
      #pragma unroll
      for (int e = 0; e < 8; ++e) acc4[h][e] = 0.f;
    #pragma unroll
    for (int j = 0; j < 8; ++j) {
      float xf[8];
      #pragma unroll
      for (int e = 0; e < 8; ++e) xf[e] = b2f((unsigned short)xv[j][e]);
      #pragma unroll
      for (int h = 0; h < 4; ++h) {
        const float wa = a_lds[nl][j*4 + h];
        #pragma unroll
        for (int e = 0; e < 8; ++e) acc4[h][e] = fmaf(wa, xf[e], acc4[h][e]);
      }
    }
    #pragma unroll
    for (int h = 0; h < 4; ++h) {
      s16x8 o;
      #pragma unroll
      for (int e = 0; e < 8; ++e) o[e] = (short)f2b(acc4[h][e]);
      *(s16x8*)&At[h][nl][ci*8] = o;
    }
  }
  __syncthreads();
  // P3: MFMA per head (wave w = head w): At[w] (32x64) @ W0b rows [64w..64w+64)
  const int w    = tid >> 6;
  const int lane = tid & 63;
  const int n16  = lane & 15;
  const int q    = lane >> 4;
  f32x4 acc[2][4];
  #pragma unroll
  for (int rt = 0; rt < 2; ++rt)
    #pragma unroll
    for (int ct = 0; ct < 4; ++ct) acc[rt][ct] = (f32x4){0.f,0.f,0.f,0.f};
  #pragma unroll
  for (int kc = 0; kc < 2; ++kc) {
    s16x8 af[2], bfr[4];
    #pragma unroll
    for (int rt = 0; rt < 2; ++rt)
      af[rt] = *(const s16x8*)&At[w][rt*16 + n16][kc*32 + q*8];
    #pragma unroll
    for (int ct = 0; ct < 4; ++ct)
      bfr[ct] = *(const s16x8*)&W0b[(size_t)((w*4 + ct)*16 + n16)*64 + kc*32 + q*8];
    #pragma unroll
    for (int rt = 0; rt < 2; ++rt)
      #pragma unroll
      for (int ct = 0; ct < 4; ++ct)
        acc[rt][ct] = __builtin_amdgcn_mfma_f32_16x16x32_bf16(af[rt], bfr[ct], acc[rt][ct], 0, 0, 0);
  }
  // P4: elu (in-place in acc) + el1/er1 partial dots (vl1/vr1 straight from L2)
  {
    float vl1v[4][4], vr1v[4][4];
    #pragma unroll
    for (int h = 0; h < 4; ++h)
      #pragma unroll
      for (int ct = 0; ct < 4; ++ct) {
        vl1v[h][ct] = vl1g[h*256 + w*64 + ct*16 + n16];
        vr1v[h][ct] = vr1g[h*256 + w*64 + ct*16 + n16];
      }
    #pragma unroll
    for (int rt = 0; rt < 2; ++rt) {
      #pragma unroll
      for (int reg = 0; reg < 4; ++reg) {
        const int row = rt*16 + q*4 + reg;
        #pragma unroll
        for (int ct = 0; ct < 4; ++ct) acc[rt][ct][reg] = eluf(acc[rt][ct][reg]);
        float ep[4], rp[4];
        #pragma unroll
        for (int h = 0; h < 4; ++h) {
          ep[h] = acc[rt][0][reg]*vl1v[h][0] + acc[rt][1][reg]*vl1v[h][1]
                + acc[rt][2][reg]*vl1v[h][2] + acc[rt][3][reg]*vl1v[h][3];
          rp[h] = acc[rt][0][reg]*vr1v[h][0] + acc[rt][1][reg]*vr1v[h][1]
                + acc[rt][2][reg]*vr1v[h][2] + acc[rt][3][reg]*vr1v[h][3];
        }
        #pragma unroll
        for (int o = 1; o < 16; o <<= 1)
          #pragma unroll
          for (int h = 0; h < 4; ++h) { ep[h] += __shfl_xor(ep[h], o); rp[h] += __shfl_xor(rp[h], o); }
        if (n16 == 0)
          #pragma unroll
          for (int h = 0; h < 4; ++h) { elpart[w][row][h] = ep[h]; erpart[w][row][h] = rp[h]; }
      }
    }
  }
  __syncthreads();   // all At reads done; reuse as h1 bounce
  {
    unsigned short* Hb = &At[0][0][0];   // [32][256]
    #pragma unroll
    for (int rt = 0; rt < 2; ++rt)
      #pragma unroll
      for (int reg = 0; reg < 4; ++reg) {
        const int row = rt*16 + q*4 + reg;
        #pragma unroll
        for (int ct = 0; ct < 4; ++ct)
          Hb[row*256 + w*64 + ct*16 + n16] = f2b(acc[rt][ct][reg]);
      }
  }
  __syncthreads();
  // P6: coalesced h1b write + el1/er1 wave-sum
  {
    const unsigned short* Hb = &At[0][0][0];
    #pragma unroll
    for (int i = 0; i < 4; ++i) {
      int u = tid + i*256;
      int row = u >> 5, off = (u & 31) * 8;
      *(s16x8*)&h1b[(size_t)((nBase + row)*32 + bt)*256 + off] = *(const s16x8*)&Hb[row*256 + off];
    }
    if (tid < 128) {
      const int row = tid >> 2, h = tid & 3;
      float se = 0.f, sr = 0.f;
      #pragma unroll
      for (int ww = 0; ww < 4; ++ww) { se += elpart[ww][row][h]; sr += erpart[ww][row][h]; }
      const int r = (nBase + row)*32 + bt;
      el1[r*4 + h] = se;
      er1[r*4 + h] = sr;
    }
  }
}

// ---- layer 1 + proj: gather h1 -> g1, MFMA g1@W1^T, +h1 residual, elu, proj ----
__global__ __launch_bounds__(256, 4) void k_l1(
    const unsigned short* __restrict__ h1b, const float* __restrict__ el,
    const float* __restrict__ er, const int* __restrict__ src,
    const unsigned short* __restrict__ W1b, const float* __restrict__ W2,
    const float* __restrict__ Wres2, float* __restrict__ feat2, float* __restrict__ res2)
{
  __shared__ float wsm[32][8][4];
  __shared__ int   ssm[32][8];
  __shared__ __align__(16) unsigned short At[32][264];   // 16896 B; pp overlays after MFMA
  __shared__ __align__(16) unsigned short own[32][264];
  const int tid = threadIdx.x;
  const int g     = blockIdx.x & 7;
  const int bt    = g*4 + ((blockIdx.x >> 3) & 3);
  const int nBase = (blockIdx.x >> 5) * 32;
  ((int*)ssm)[tid] = src[nBase*8 + tid];
  __syncthreads();
  if (tid < 128) {
    const int nl = tid >> 2, h = tid & 3;
    const int rn = (nBase + nl)*32 + bt;
    const float erv = er[rn*4 + h];
    float e[8]; float mx = -1e30f;
    #pragma unroll
    for (int j = 0; j < 8; ++j) {
      float v = el[(ssm[nl][j]*32 + bt)*4 + h] + erv;
      v = v >= 0.f ? v : NEGS * v;
      e[j] = v; mx = fmaxf(mx, v);
    }
    float den = 0.f;
    #pragma unroll
    for (int j = 0; j < 8; ++j) { e[j] = __expf(e[j] - mx); den += e[j]; }
    const float inv = 1.f / den;
    #pragma unroll
    for (int j = 0; j < 8; ++j) wsm[nl][j][h] = e[j] * inv;
  }
  __syncthreads();
  // PB: gather + weighted sum -> At (g1); stage own rows coalesced
  {
    const int hw2 = tid >> 5, l5 = tid & 31;
    const int c0 = l5 * 8, hh = l5 >> 3;
    #pragma unroll
    for (int p2 = 0; p2 < 2; ++p2) {
      const int nlA = p2*16 + hw2, nlB = nlA + 8;
      s16x8 vA[8], vB[8];
      #pragma unroll
      for (int j = 0; j < 8; ++j) {
        vA[j] = *(const s16x8*)&h1b[(size_t)(ssm[nlA][j]*32 + bt)*256 + c0];
        vB[j] = *(const s16x8*)&h1b[(size_t)(ssm[nlB][j]*32 + bt)*256 + c0];
      }
      asm volatile("" ::: "memory");
      float aA[8] = {0,0,0,0,0,0,0,0}, aB[8] = {0,0,0,0,0,0,0,0};
      #pragma unroll
      for (int j = 0; j < 8; ++j) {
        const float wA = wsm[nlA][j][hh], wB = wsm[nlB][j][hh];
        #pragma unroll
        for (int i = 0; i < 8; ++i) {
          aA[i] = fmaf(wA, b2f((unsigned short)vA[j][i]), aA[i]);
          aB[i] = fmaf(wB, b2f((unsigned short)vB[j][i]), aB[i]);
        }
      }
      s16x8 oA, oB;
      #pragma unroll
      for (int i = 0; i < 8; ++i) { oA[i] = (short)f2b(aA[i]); oB[i] = (short)f2b(aB[i]); }
      *(s16x8*)&At[nlA][c0] = oA;
      *(s16x8*)&At[nlB][c0] = oB;
    }
    #pragma unroll
    for (int i = 0; i < 4; ++i) {
      int u = tid + i*256;
      int row = u >> 5, off = (u & 31) * 8;
      *(s16x8*)&own[row][off] = *(const s16x8*)&h1b[(size_t)((nBase + row)*32 + bt)*256 + off];
    }
  }
  __syncthreads();
  // PC: MFMA g1 @ W1^T (32x256x256), W1b from L2
  const int w    = tid >> 6;
  const int lane = tid & 63;
  const int n16  = lane & 15;
  const int q    = lane >> 4;
  f32x4 acc[2][4];
  #pragma unroll
  for (int rt = 0; rt < 2; ++rt)
    #pragma unroll
    for (int ct = 0; ct < 4; ++ct) acc[rt][ct] = (f32x4){0.f,0.f,0.f,0.f};
  #pragma unroll
  for (int kc = 0; kc < 8; ++kc) {
    s16x8 af[2], bfr[4];
    #pragma unroll
    for (int rt = 0; rt < 2; ++rt)
      af[rt] = *(const s16x8*)&At[rt*16 + n16][kc*32 + q*8];
    #pragma unroll
    for (int ct = 0; ct < 4; ++ct)
      bfr[ct] = *(const s16x8*)&W1b[(size_t)((w*4 + ct)*16 + n16)*256 + kc*32 + q*8];
    #pragma unroll
    for (int rt = 0; rt < 2; ++rt)
      #pragma unroll
      for (int ct = 0; ct < 4; ++ct)
        acc[rt][ct] = __builtin_amdgcn_mfma_f32_16x16x32_bf16(af[rt], bfr[ct], acc[rt][ct], 0, 0, 0);
  }
  __syncthreads();   // At reads done; pp overlays At
  // PD: h2 = elu(acc + own); proj partials -> pp
  {
    float* pp = (float*)&At[0][0];   // [4][32][8]
    float wpv[8][4];
    #pragma unroll
    for (int o = 0; o < 8; ++o) {
      const float* Wsrc = (o < 4) ? W2 : Wres2;
      #pragma unroll
      for (int ct = 0; ct < 4; ++ct)
        wpv[o][ct] = Wsrc[(o & 3)*256 + w*64 + ct*16 + n16];
    }
    #pragma unroll
    for (int rt = 0; rt < 2; ++rt) {
      #pragma unroll
      for (int reg = 0; reg < 4; ++reg) {
        const int row = rt*16 + q*4 + reg;
        float h2[4];
        #pragma unroll
        for (int ct = 0; ct < 4; ++ct)
          h2[ct] = eluf(acc[rt][ct][reg] + b2f(own[row][w*64 + ct*16 + n16]));
        float pf[8];
        #pragma unroll
        for (int o = 0; o < 8; ++o)
          pf[o] = h2[0]*wpv[o][0] + h2[1]*wpv[o][1] + h2[2]*wpv[o][2] + h2[3]*wpv[o][3];
        #pragma unroll
        for (int of = 1; of < 16; of <<= 1)
          #pragma unroll
          for (int o = 0; o < 8; ++o) pf[o] += __shfl_xor(pf[o], of);
        if (n16 == 0)
          #pragma unroll
          for (int o = 0; o < 8; ++o) pp[(w*32 + row)*8 + o] = pf[o];
      }
    }
  }
  __syncthreads();
  // PE: reduce across waves, write feat2/res2
  {
    const float* pp = (const float*)&At[0][0];
    const int row = tid >> 3, o = tid & 7;
    float s = pp[(0*32 + row)*8 + o] + pp[(1*32 + row)*8 + o]
            + pp[(2*32 + row)*8 + o] + pp[(3*32 + row)*8 + o];
    const int rn = (nBase + row)*32 + bt;
    if (o < 4) feat2[rn*4 + o] = s;
    else       res2[rn*4 + (o-4)] = s;
  }
}

// ---------------- layer 2 aggregate + tc1 einsum -> x1[b][o][n] ----------------
__global__ __launch_bounds__(128) void k_agg2(
    const float* __restrict__ feat2, const float* __restrict__ res2,
    const int* __restrict__ src, const float* __restrict__ al2,
    const float* __restrict__ ar2, const float* __restrict__ tc1w,
    const float* __restrict__ tc1b, float* __restrict__ x1)
{
  __shared__ float os[4][8][4];   // [b][t][h]
  const int n = blockIdx.x;
  const int tid = threadIdx.x;
  const int b = tid >> 5, t = (tid >> 2) & 7, h = tid & 3;
  const int rn = n*32 + b*8 + t;
  const float av = al2[h], rv = ar2[h];
  const float erv = feat2[rn*4 + h] * rv;
  float f[8], e[8]; float m = -1e30f;
  #pragma unroll
  for (int j = 0; j < 8; ++j) {
    int s_ = src[n*8 + j];
    f[j] = feat2[(s_*32 + b*8 + t)*4 + h];
    float v = f[j]*av + erv;
    v = v >= 0.f ? v : NEGS * v;
    e[j] = v; m = fmaxf(m, v);
  }
  float den = 0.f, num = 0.f;
  #pragma unroll
  for (int j = 0; j < 8; ++j) { float ex = __expf(e[j]-m); den += ex; num = fmaf(ex, f[j], num); }
  os[b][t][h] = num/den + res2[rn*4 + h];
  __syncthreads();
  if (tid < 16) {
    int b2 = tid >> 2, o2 = tid & 3;
    float acc = tc1b[o2];
    #pragma unroll
    for (int hh = 0; hh < 4; ++hh)
      #pragma unroll
      for (int tt = 0; tt < 8; ++tt)
        acc = fmaf(tc1w[(o2*4 + hh)*8 + tt], os[b2][tt][hh], acc);
    x1[(b2*4 + o2)*1024 + n] = acc;
  }
}

// ---------------- head: LN1 -> tc2 -> LN2 -> conv -> out (B x 7) ----------------
__global__ __launch_bounds__(1024) void k_final(
    const float* __restrict__ x1, const float* __restrict__ ln1g,
    const float* __restrict__ ln1b, const float* __restrict__ tc2w,
    const float* __restrict__ tc2b, const float* __restrict__ ln2g,
    const float* __restrict__ ln2b, const float* __restrict__ fcw,
    const float* __restrict__ fcb, float* __restrict__ out)
{
  __shared__ float red[16];
  __shared__ float x2s[1024];
  const int b = blockIdx.x;
  const int tid = threadIdx.x;
  float s = 0.f, q = 0.f;
  for (int j = tid; j < 4096; j += 1024) {
    float v = x1[b*4096 + j];
    s += v; q += v*v;
  }
  float S = block_reduce1024(s, red);
  float Q = block_reduce1024(q, red);
  float mu  = S * (1.f/4096.f);
  float var = Q * (1.f/4096.f) - mu*mu;
  float inv = rsqrtf(var + EPSF);
  float tb = tc2b[0];
  const int nn = tid;
  float acc = tb;
  #pragma unroll
  for (int h = 0; h < 4; ++h) {
    float z = (x1[b*4096 + h*1024 + nn] - mu) * inv * ln1g[nn*4 + h] + ln1b[nn*4 + h];
    acc = fmaf(tc2w[h], z, acc);
  }
  float S2 = block_reduce1024(acc, red);
  float Q2 = block_reduce1024(acc*acc, red);
  float mu2  = S2 * (1.f/1024.f);
  float inv2 = rsqrtf(Q2 * (1.f/1024.f) - mu2*mu2 + EPSF);
  x2s[nn] = (acc - mu2) * inv2 * ln2g[nn] + ln2b[nn];
  __syncthreads();
  for (int c = 0; c < 7; ++c) {
    float p = (tid < 1018) ? x2s[c + tid] * fcw[tid] : 0.f;
    float P = block_reduce1024(p, red);
    if (tid == 0) out[b*7 + c] = P + fcb[0];
  }
}

extern "C" void kernel_launch(void* const* d_in, const int* in_sizes, int n_in,
                              void* d_out, int out_size, void* d_ws, size_t ws_size,
                              hipStream_t stream)
{
  const float* inp  = (const float*)d_in[0];
  const int*   src  = (const int*)  d_in[1];
  const float* W0   = (const float*)d_in[3];
  const float* al0  = (const float*)d_in[4];
  const float* ar0  = (const float*)d_in[5];
  const float* W1   = (const float*)d_in[6];
  const float* al1  = (const float*)d_in[7];
  const float* ar1  = (const float*)d_in[8];
  const float* W2   = (const float*)d_in[9];
  const float* al2  = (const float*)d_in[10];
  const float* ar2  = (const float*)d_in[11];
  const float* Wr2  = (const float*)d_in[12];
  const float* tc1w = (const float*)d_in[13];
  const float* tc1b = (const float*)d_in[14];
  const float* ln1g = (const float*)d_in[15];
  const float* ln1b = (const float*)d_in[16];
  const float* tc2w = (const float*)d_in[17];
  const float* tc2b = (const float*)d_in[18];
  const float* ln2g = (const float*)d_in[19];
  const float* ln2b = (const float*)d_in[20];
  const float* fcw  = (const float*)d_in[21];
  const float* fcb  = (const float*)d_in[22];
  float* out = (float*)d_out;

  unsigned short* Xb   = (unsigned short*)d_ws;   // 2,097,152
  unsigned short* W0b  = Xb  + 2097152;           // 16,384
  unsigned short* W1b  = W0b + 16384;             // 65,536
  unsigned short* h1b  = W1b + 65536;             // 8,388,608
  float* vl0g  = (float*)(h1b + 8388608);         // 256
  float* vr0g  = vl0g + 256;
  float* vl1g  = vr0g + 256;                      // 1024
  float* vr1g  = vl1g + 1024;
  float* el0g  = vr1g + 1024;                     // 131,072
  float* er0g  = el0g + 131072;
  float* el1   = er0g + 131072;
  float* er1   = el1 + 131072;
  float* feat2 = er1 + 131072;
  float* res2  = feat2 + 131072;
  float* x1    = res2 + 131072;                   // 16,384

  k_pre0<<<dim3(65), dim3(256), 0, stream>>>(W0, W1, al0, ar0, al1, ar1,
                                             W0b, W1b, vl0g, vr0g, vl1g, vr1g);
  k_pre1<<<dim3(512), dim3(256), 0, stream>>>(inp, vl0g, vr0g, Xb, el0g, er0g);
  k_l0<<<dim3(1024), dim3(256), 0, stream>>>(Xb, src, W0b, el0g, er0g, vl1g, vr1g,
                                             h1b, el1, er1);
  k_l1<<<dim3(1024), dim3(256), 0, stream>>>(h1b, el1, er1, src, W1b, W2, Wr2,
                                             feat2, res2);
  k_agg2<<<dim3(1024), dim3(128), 0, stream>>>(feat2, res2, src, al2, ar2, tc1w, tc1b, x1);
  k_final<<<dim3(4), dim3(1024), 0, stream>>>(x1, ln1g, ln1b, tc2w, tc2b, ln2g, ln2b, fcw, fcb, out);
}

// Round 14
// 170.434 us; speedup vs baseline: 1.2915x; 1.1489x over previous
//
#include <hip/hip_runtime.h>
#include <math.h>

#define NEGS 0.2f
#define EPSF 1e-5f

typedef short s16x8 __attribute__((ext_vector_type(8)));
typedef float f32x4 __attribute__((ext_vector_type(4)));

__device__ __forceinline__ float b2f(unsigned short u) {
  union { unsigned int i; float f; } v; v.i = ((unsigned int)u) << 16; return v.f;
}
__device__ __forceinline__ unsigned short f2b(float f) {
  union { float f; unsigned int i; } v; v.f = f;
  unsigned int x = v.i;
  return (unsigned short)((x + 0x7fffu + ((x >> 16) & 1u)) >> 16);
}

__device__ __forceinline__ float block_reduce1024(float v, float* red) {
  #pragma unroll
  for (int o = 32; o > 0; o >>= 1) v += __shfl_down(v, o);
  __syncthreads();
  if ((threadIdx.x & 63) == 0) red[threadIdx.x >> 6] = v;
  __syncthreads();
  float s = 0.f;
  #pragma unroll
  for (int i = 0; i < 16; ++i) s += red[i];
  return s;
}

// ---- layer-0: feat0 = (inp^T) @ W0^T. XCD-swizzled: XCD g (blockIdx%8) owns bt in [4g,4g+4).
__global__ __launch_bounds__(256) void k_feat0(
    const float* __restrict__ inp, const float* __restrict__ W0,
    const float* __restrict__ W1, const float* __restrict__ al,
    const float* __restrict__ ar, unsigned short* __restrict__ feat,
    float* __restrict__ el, float* __restrict__ er,
    unsigned short* __restrict__ W1b)
{
  const int tid = threadIdx.x;
  if (blockIdx.x >= 512) {
    const int j = (blockIdx.x - 512) * 256 + tid;   // [0,16384)
    float4 w4 = *(const float4*)&W1[j*4];
    ushort4 o4; o4.x=f2b(w4.x); o4.y=f2b(w4.y); o4.z=f2b(w4.z); o4.w=f2b(w4.w);
    *(ushort4*)&W1b[j*4] = o4;
    return;
  }
  __shared__ __align__(16) unsigned short At[64][72];   // A-tile [node][ch]
  __shared__ __align__(16) unsigned short Lb[64*256];   // C bounce
  const int g  = blockIdx.x & 7;
  const int bt = g*4 + ((blockIdx.x >> 3) & 3);         // XCD-aligned bt slice
  const int n0 = (blockIdx.x >> 5) * 64;
  const int b  = bt >> 3, t = bt & 7;
  const int w    = tid >> 6;
  const int lane = tid & 63;
  const int n16  = lane & 15;
  const int q    = lane >> 4;
  s16x8 bf[2][4];   // W0 fragments in registers
  #pragma unroll
  for (int kc = 0; kc < 2; ++kc)
    #pragma unroll
    for (int ct = 0; ct < 4; ++ct) {
      const float* p = &W0[(size_t)((w*4 + ct)*16 + n16)*64 + kc*32 + q*8];
      float4 wa = *(const float4*)p;
      float4 wb = *(const float4*)(p + 4);
      s16x8 o;
      o[0]=(short)f2b(wa.x); o[1]=(short)f2b(wa.y); o[2]=(short)f2b(wa.z); o[3]=(short)f2b(wa.w);
      o[4]=(short)f2b(wb.x); o[5]=(short)f2b(wb.y); o[6]=(short)f2b(wb.z); o[7]=(short)f2b(wb.w);
      bf[kc][ct] = o;
    }
  {
    const int nn = tid & 63, cg = tid >> 6;
    #pragma unroll
    for (int c2 = 0; c2 < 8; ++c2) {
      int ch = (cg*8 + c2) * 2;
      float vx = inp[((size_t)(b*64 + ch  )*8 + t)*1024 + n0 + nn];
      float vy = inp[((size_t)(b*64 + ch+1)*8 + t)*1024 + n0 + nn];
      unsigned int pk = ((unsigned int)f2b(vy) << 16) | (unsigned int)f2b(vx);
      *(unsigned int*)&At[nn][ch] = pk;
    }
  }
  __syncthreads();
  f32x4 acc[4][4];
  #pragma unroll
  for (int rt = 0; rt < 4; ++rt)
    #pragma unroll
    for (int ct = 0; ct < 4; ++ct) acc[rt][ct] = (f32x4){0.f,0.f,0.f,0.f};
  #pragma unroll
  for (int kc = 0; kc < 2; ++kc) {
    s16x8 af[4];
    #pragma unroll
    for (int rt = 0; rt < 4; ++rt)
      af[rt] = *(const s16x8*)&At[rt*16 + n16][kc*32 + q*8];
    #pragma unroll
    for (int rt = 0; rt < 4; ++rt)
      #pragma unroll
      for (int ct = 0; ct < 4; ++ct)
        acc[rt][ct] = __builtin_amdgcn_mfma_f32_16x16x32_bf16(af[rt], bf[kc][ct], acc[rt][ct], 0, 0, 0);
  }
  float alv[4], arv[4];
  #pragma unroll
  for (int ct = 0; ct < 4; ++ct) {
    alv[ct] = al[w*64 + ct*16 + n16];
    arv[ct] = ar[w*64 + ct*16 + n16];
  }
  #pragma unroll
  for (int rt = 0; rt < 4; ++rt) {
    #pragma unroll
    for (int reg = 0; reg < 4; ++reg) {
      float pl = acc[rt][0][reg]*alv[0] + acc[rt][1][reg]*alv[1]
               + acc[rt][2][reg]*alv[2] + acc[rt][3][reg]*alv[3];
      float pr = acc[rt][0][reg]*arv[0] + acc[rt][1][reg]*arv[1]
               + acc[rt][2][reg]*arv[2] + acc[rt][3][reg]*arv[3];
      #pragma unroll
      for (int o = 1; o < 16; o <<= 1) { pl += __shfl_xor(pl, o); pr += __shfl_xor(pr, o); }
      if (n16 == 0) {
        int r = (n0 + rt*16 + q*4 + reg)*32 + bt;
        el[r*4 + w] = pl;
        er[r*4 + w] = pr;
      }
    }
  }
  #pragma unroll
  for (int rt = 0; rt < 4; ++rt)
    #pragma unroll
    for (int ct = 0; ct < 4; ++ct)
      #pragma unroll
      for (int reg = 0; reg < 4; ++reg)
        Lb[(rt*16 + q*4 + reg)*256 + w*64 + ct*16 + n16] = f2b(acc[rt][ct][reg]);
  __syncthreads();
  #pragma unroll
  for (int i = 0; i < 8; ++i) {
    int u = tid + i*256;
    int m = u >> 5, off = (u & 31) * 8;
    *(s16x8*)&feat[(size_t)((n0 + m)*32 + bt)*256 + off] = *(const s16x8*)&Lb[m*256 + off];
  }
}

// ------- agg0 + feat1, bt-sliced: block = (bt, 32-node chunk), same XCD swizzle. -------
__global__ __launch_bounds__(256, 4) void k_agg0_feat1(
    const unsigned short* __restrict__ feat0, const float* __restrict__ el0,
    const float* __restrict__ er0, const int* __restrict__ src,
    const unsigned short* __restrict__ W1b, const float* __restrict__ al,
    const float* __restrict__ ar, unsigned short* __restrict__ h1b,
    unsigned short* __restrict__ feat1, float* __restrict__ el1, float* __restrict__ er1)
{
  __shared__ float wsm[32][8][4];            // [node_local][j][h]
  __shared__ int   ssm[32][8];
  __shared__ __align__(16) unsigned short smbuf[32*264];  // A-tile (padded) / bounce
  unsigned short (*At)[264] = (unsigned short(*)[264])smbuf;
  unsigned short *Lb = smbuf;
  const int tid = threadIdx.x;
  const int g     = blockIdx.x & 7;
  const int bt    = g*4 + ((blockIdx.x >> 3) & 3);
  const int nBase = (blockIdx.x >> 5) * 32;
  ((int*)ssm)[tid] = src[nBase*8 + tid];
  __syncthreads();
  if (tid < 128) {
    const int nl = tid >> 2, h = tid & 3;
    const int rn = (nBase + nl)*32 + bt;
    const float erv = er0[rn*4 + h];
    float e[8]; float mx = -1e30f;
    #pragma unroll
    for (int j = 0; j < 8; ++j) {
      float v = el0[(ssm[nl][j]*32 + bt)*4 + h] + erv;
      v = v >= 0.f ? v : NEGS * v;
      e[j] = v; mx = fmaxf(mx, v);
    }
    float den = 0.f;
    #pragma unroll
    for (int j = 0; j < 8; ++j) { e[j] = __expf(e[j] - mx); den += e[j]; }
    const float inv = 1.f / den;
    #pragma unroll
    for (int j = 0; j < 8; ++j) wsm[nl][j][h] = e[j] * inv;
  }
  __syncthreads();
  // phase B: half-wave per node, 2 nodes per pass (16 loads in flight)
  {
    const int hw2 = tid >> 5, l5 = tid & 31;
    const int c0 = l5 * 8, hh = l5 >> 3;
    #pragma unroll
    for (int p2 = 0; p2 < 2; ++p2) {
      const int nlA = p2*16 + hw2, nlB = nlA + 8;
      s16x8 vA[8], vB[8];
      #pragma unroll
      for (int j = 0; j < 8; ++j) {
        vA[j] = *(const s16x8*)&feat0[(size_t)(ssm[nlA][j]*32 + bt)*256 + c0];
        vB[j] = *(const s16x8*)&feat0[(size_t)(ssm[nlB][j]*32 + bt)*256 + c0];
      }
      asm volatile("" ::: "memory");
      float aA[8] = {0,0,0,0,0,0,0,0}, aB[8] = {0,0,0,0,0,0,0,0};
      #pragma unroll
      for (int j = 0; j < 8; ++j) {
        const float wA = wsm[nlA][j][hh], wB = wsm[nlB][j][hh];
        #pragma unroll
        for (int i = 0; i < 8; ++i) {
          aA[i] = fmaf(wA, b2f((unsigned short)vA[j][i]), aA[i]);
          aB[i] = fmaf(wB, b2f((unsigned short)vB[j][i]), aB[i]);
        }
      }
      s16x8 oA, oB;
      #pragma unroll
      for (int i = 0; i < 8; ++i) {
        float xA = aA[i] > 0.f ? aA[i] : expm1f(aA[i]);
        float xB = aB[i] > 0.f ? aB[i] : expm1f(aB[i]);
        oA[i] = (short)f2b(xA); oB[i] = (short)f2b(xB);
      }
      *(s16x8*)&At[nlA][c0] = oA;
      *(s16x8*)&At[nlB][c0] = oB;
      *(s16x8*)&h1b[(size_t)((nBase + nlA)*32 + bt)*256 + c0] = oA;
      *(s16x8*)&h1b[(size_t)((nBase + nlB)*32 + bt)*256 + c0] = oB;
    }
  }
  __syncthreads();
  // phase C: MFMA 32x256 vs W1 (L2-resident). A-rows = 32 nodes at fixed bt.
  const int w    = tid >> 6;
  const int lane = tid & 63;
  const int n16  = lane & 15;
  const int q    = lane >> 4;
  f32x4 acc[2][4];
  #pragma unroll
  for (int rt = 0; rt < 2; ++rt)
    #pragma unroll
    for (int ct = 0; ct < 4; ++ct) acc[rt][ct] = (f32x4){0.f,0.f,0.f,0.f};
  #pragma unroll
  for (int kc = 0; kc < 8; ++kc) {
    s16x8 af[2], bfr[4];
    #pragma unroll
    for (int rt = 0; rt < 2; ++rt)
      af[rt] = *(const s16x8*)&At[rt*16 + n16][kc*32 + q*8];
    #pragma unroll
    for (int ct = 0; ct < 4; ++ct)
      bfr[ct] = *(const s16x8*)&W1b[(size_t)((w*4 + ct)*16 + n16)*256 + kc*32 + q*8];
    #pragma unroll
    for (int rt = 0; rt < 2; ++rt)
      #pragma unroll
      for (int ct = 0; ct < 4; ++ct)
        acc[rt][ct] = __builtin_amdgcn_mfma_f32_16x16x32_bf16(af[rt], bfr[ct], acc[rt][ct], 0, 0, 0);
  }
  float alv[4], arv[4];
  #pragma unroll
  for (int ct = 0; ct < 4; ++ct) {
    alv[ct] = al[w*64 + ct*16 + n16];
    arv[ct] = ar[w*64 + ct*16 + n16];
  }
  #pragma unroll
  for (int rt = 0; rt < 2; ++rt) {
    #pragma unroll
    for (int reg = 0; reg < 4; ++reg) {
      float pl = acc[rt][0][reg]*alv[0] + acc[rt][1][reg]*alv[1]
               + acc[rt][2][reg]*alv[2] + acc[rt][3][reg]*alv[3];
      float pr = acc[rt][0][reg]*arv[0] + acc[rt][1][reg]*arv[1]
               + acc[rt][2][reg]*arv[2] + acc[rt][3][reg]*arv[3];
      #pragma unroll
      for (int o = 1; o < 16; o <<= 1) { pl += __shfl_xor(pl, o); pr += __shfl_xor(pr, o); }
      if (n16 == 0) {
        int r = (nBase + rt*16 + q*4 + reg)*32 + bt;
        el1[r*4 + w] = pl;
        er1[r*4 + w] = pr;
      }
    }
  }
  __syncthreads();
  #pragma unroll
  for (int rt = 0; rt < 2; ++rt)
    #pragma unroll
    for (int ct = 0; ct < 4; ++ct)
      #pragma unroll
      for (int reg = 0; reg < 4; ++reg)
        Lb[(rt*16 + q*4 + reg)*256 + w*64 + ct*16 + n16] = f2b(acc[rt][ct][reg]);
  __syncthreads();
  #pragma unroll
  for (int i = 0; i < 4; ++i) {
    int u = tid + i*256;
    int row = u >> 5, off = (u & 31) * 8;
    *(s16x8*)&feat1[(size_t)((nBase + row)*32 + bt)*256 + off] = *(const s16x8*)&Lb[row*256 + off];
  }
}

// ------- agg1 + proj, bt-sliced: h2 = elu(Agg(feat1)+h1); feat2/res2 = h2 @ [W2;Wres2]^T -------
__global__ __launch_bounds__(256, 4) void k_agg1_proj(
    const unsigned short* __restrict__ feat1, const float* __restrict__ el,
    const float* __restrict__ er, const int* __restrict__ src,
    const unsigned short* __restrict__ h1b, const float* __restrict__ W2,
    const float* __restrict__ Wres2, float* __restrict__ feat2, float* __restrict__ res2)
{
  __shared__ float wsm[32][8][4];
  __shared__ int   ssm[32][8];
  __shared__ __align__(16) float Wp[8][256];
  const int tid = threadIdx.x;
  const int g     = blockIdx.x & 7;
  const int bt    = g*4 + ((blockIdx.x >> 3) & 3);
  const int nBase = (blockIdx.x >> 5) * 32;
  ((int*)ssm)[tid] = src[nBase*8 + tid];
  for (int j2 = tid; j2 < 2048; j2 += 256) {
    int o = j2 >> 8, k = j2 & 255;
    Wp[o][k] = (o < 4) ? W2[o*256 + k] : Wres2[(o-4)*256 + k];
  }
  __syncthreads();
  if (tid < 128) {
    const int nl = tid >> 2, h = tid & 3;
    const int rn = (nBase + nl)*32 + bt;
    const float erv = er[rn*4 + h];
    float e[8]; float mx = -1e30f;
    #pragma unroll
    for (int j = 0; j < 8; ++j) {
      float v = el[(ssm[nl][j]*32 + bt)*4 + h] + erv;
      v = v >= 0.f ? v : NEGS * v;
      e[j] = v; mx = fmaxf(mx, v);
    }
    float den = 0.f;
    #pragma unroll
    for (int j = 0; j < 8; ++j) { e[j] = __expf(e[j] - mx); den += e[j]; }
    const float inv = 1.f / den;
    #pragma unroll
    for (int j = 0; j < 8; ++j) wsm[nl][j][h] = e[j] * inv;
  }
  __syncthreads();
  const int hw2 = tid >> 5, l5 = tid & 31;
  const int c0 = l5 * 8, hh = l5 >> 3;
  #pragma unroll
  for (int p2 = 0; p2 < 2; ++p2) {
    const int nlA = p2*16 + hw2, nlB = nlA + 8;
    const int rnA = (nBase + nlA)*32 + bt, rnB = (nBase + nlB)*32 + bt;
    s16x8 vA[8], vB[8], rrA, rrB;
    rrA = *(const s16x8*)&h1b[(size_t)rnA*256 + c0];
    rrB = *(const s16x8*)&h1b[(size_t)rnB*256 + c0];
    #pragma unroll
    for (int j = 0; j < 8; ++j) {
      vA[j] = *(const s16x8*)&feat1[(size_t)(ssm[nlA][j]*32 + bt)*256 + c0];
      vB[j] = *(const s16x8*)&feat1[(size_t)(ssm[nlB][j]*32 + bt)*256 + c0];
    }
    asm volatile("" ::: "memory");
    float aA[8] = {0,0,0,0,0,0,0,0}, aB[8] = {0,0,0,0,0,0,0,0};
    #pragma unroll
    for (int j = 0; j < 8; ++j) {
      const float wA = wsm[nlA][j][hh], wB = wsm[nlB][j][hh];
      #pragma unroll
      for (int i = 0; i < 8; ++i) {
        aA[i] = fmaf(wA, b2f((unsigned short)vA[j][i]), aA[i]);
        aB[i] = fmaf(wB, b2f((unsigned short)vB[j][i]), aB[i]);
      }
    }
    #pragma unroll
    for (int i = 0; i < 8; ++i) {
      float xA = aA[i] + b2f((unsigned short)rrA[i]);
      float xB = aB[i] + b2f((unsigned short)rrB[i]);
      aA[i] = xA > 0.f ? xA : expm1f(xA);
      aB[i] = xB > 0.f ? xB : expm1f(xB);
    }
    #pragma unroll
    for (int o = 0; o < 8; ++o) {
      float4 wa = *(const float4*)&Wp[o][c0];
      float4 wb = *(const float4*)&Wp[o][c0 + 4];
      float pA = aA[0]*wa.x + aA[1]*wa.y + aA[2]*wa.z + aA[3]*wa.w
               + aA[4]*wb.x + aA[5]*wb.y + aA[6]*wb.z + aA[7]*wb.w;
      float pB = aB[0]*wa.x + aB[1]*wa.y + aB[2]*wa.z + aB[3]*wa.w
               + aB[4]*wb.x + aB[5]*wb.y + aB[6]*wb.z + aB[7]*wb.w;
      #pragma unroll
      for (int off = 1; off < 32; off <<= 1) {
        pA += __shfl_xor(pA, off);
        pB += __shfl_xor(pB, off);
      }
      if (l5 == 0) {
        if (o < 4) { feat2[rnA*4 + o] = pA; feat2[rnB*4 + o] = pB; }
        else       { res2[rnA*4 + (o-4)] = pA; res2[rnB*4 + (o-4)] = pB; }
      }
    }
  }
}

// ---------------- layer 2 aggregate + tc1 einsum -> x1[b][o][n] ----------------
__global__ __launch_bounds__(128) void k_agg2(
    const float* __restrict__ feat2, const float* __restrict__ res2,
    const int* __restrict__ src, const float* __restrict__ al2,
    const float* __restrict__ ar2, const float* __restrict__ tc1w,
    const float* __restrict__ tc1b, float* __restrict__ x1)
{
  __shared__ float os[4][8][4];   // [b][t][h]
  const int n = blockIdx.x;
  const int tid = threadIdx.x;
  const int b = tid >> 5, t = (tid >> 2) & 7, h = tid & 3;
  const int rn = n*32 + b*8 + t;
  const float av = al2[h], rv = ar2[h];
  const float erv = feat2[rn*4 + h] * rv;
  float f[8], e[8]; float m = -1e30f;
  #pragma unroll
  for (int j = 0; j < 8; ++j) {
    int s_ = src[n*8 + j];
    f[j] = feat2[(s_*32 + b*8 + t)*4 + h];
    float v = f[j]*av + erv;
    v = v >= 0.f ? v : NEGS * v;
    e[j] = v; m = fmaxf(m, v);
  }
  float den = 0.f, num = 0.f;
  #pragma unroll
  for (int j = 0; j < 8; ++j) { float ex = __expf(e[j]-m); den += ex; num = fmaf(ex, f[j], num); }
  os[b][t][h] = num/den + res2[rn*4 + h];
  __syncthreads();
  if (tid < 16) {
    int b2 = tid >> 2, o2 = tid & 3;
    float acc = tc1b[o2];
    #pragma unroll
    for (int hh = 0; hh < 4; ++hh)
      #pragma unroll
      for (int tt = 0; tt < 8; ++tt)
        acc = fmaf(tc1w[(o2*4 + hh)*8 + tt], os[b2][tt][hh], acc);
    x1[(b2*4 + o2)*1024 + n] = acc;
  }
}

// ---------------- head: LN1 -> tc2 -> LN2 -> conv -> out (B x 7) ----------------
__global__ __launch_bounds__(1024) void k_final(
    const float* __restrict__ x1, const float* __restrict__ ln1g,
    const float* __restrict__ ln1b, const float* __restrict__ tc2w,
    const float* __restrict__ tc2b, const float* __restrict__ ln2g,
    const float* __restrict__ ln2b, const float* __restrict__ fcw,
    const float* __restrict__ fcb, float* __restrict__ out)
{
  __shared__ float red[16];
  __shared__ float x2s[1024];
  const int b = blockIdx.x;
  const int tid = threadIdx.x;
  float s = 0.f, q = 0.f;
  for (int j = tid; j < 4096; j += 1024) {
    float v = x1[b*4096 + j];
    s += v; q += v*v;
  }
  float S = block_reduce1024(s, red);
  float Q = block_reduce1024(q, red);
  float mu  = S * (1.f/4096.f);
  float var = Q * (1.f/4096.f) - mu*mu;
  float inv = rsqrtf(var + EPSF);
  float tb = tc2b[0];
  const int nn = tid;
  float acc = tb;
  #pragma unroll
  for (int h = 0; h < 4; ++h) {
    float z = (x1[b*4096 + h*1024 + nn] - mu) * inv * ln1g[nn*4 + h] + ln1b[nn*4 + h];
    acc = fmaf(tc2w[h], z, acc);
  }
  float S2 = block_reduce1024(acc, red);
  float Q2 = block_reduce1024(acc*acc, red);
  float mu2  = S2 * (1.f/1024.f);
  float inv2 = rsqrtf(Q2 * (1.f/1024.f) - mu2*mu2 + EPSF);
  x2s[nn] = (acc - mu2) * inv2 * ln2g[nn] + ln2b[nn];
  __syncthreads();
  for (int c = 0; c < 7; ++c) {
    float p = (tid < 1018) ? x2s[c + tid] * fcw[tid] : 0.f;
    float P = block_reduce1024(p, red);
    if (tid == 0) out[b*7 + c] = P + fcb[0];
  }
}

extern "C" void kernel_launch(void* const* d_in, const int* in_sizes, int n_in,
                              void* d_out, int out_size, void* d_ws, size_t ws_size,
                              hipStream_t stream)
{
  const float* inp  = (const float*)d_in[0];
  const int*   src  = (const int*)  d_in[1];
  const float* W0   = (const float*)d_in[3];
  const float* al0  = (const float*)d_in[4];
  const float* ar0  = (const float*)d_in[5];
  const float* W1   = (const float*)d_in[6];
  const float* al1  = (const float*)d_in[7];
  const float* ar1  = (const float*)d_in[8];
  const float* W2   = (const float*)d_in[9];
  const float* al2  = (const float*)d_in[10];
  const float* ar2  = (const float*)d_in[11];
  const float* Wr2  = (const float*)d_in[12];
  const float* tc1w = (const float*)d_in[13];
  const float* tc1b = (const float*)d_in[14];
  const float* ln1g = (const float*)d_in[15];
  const float* ln1b = (const float*)d_in[16];
  const float* tc2w = (const float*)d_in[17];
  const float* tc2b = (const float*)d_in[18];
  const float* ln2g = (const float*)d_in[19];
  const float* ln2b = (const float*)d_in[20];
  const float* fcw  = (const float*)d_in[21];
  const float* fcb  = (const float*)d_in[22];
  float* out = (float*)d_out;

  unsigned short* W1b    = (unsigned short*)d_ws;    // 65,536
  unsigned short* featb0 = W1b    + 65536;           // 8,388,608
  unsigned short* featb1 = featb0 + 8388608;         // 8,388,608
  unsigned short* h1b    = featb1 + 8388608;         // 8,388,608
  float* el0   = (float*)(h1b + 8388608);            // 131,072
  float* er0   = el0   + 131072;
  float* el1   = er0   + 131072;
  float* er1   = el1   + 131072;
  float* feat2 = er1   + 131072;
  float* res2  = feat2 + 131072;
  float* x1    = res2  + 131072;                     // 16,384

  k_feat0<<<dim3(576), dim3(256), 0, stream>>>(inp, W0, W1, al0, ar0,
                                               featb0, el0, er0, W1b);
  k_agg0_feat1<<<dim3(1024), dim3(256), 0, stream>>>(featb0, el0, er0, src, W1b, al1, ar1,
                                                     h1b, featb1, el1, er1);
  k_agg1_proj<<<dim3(1024), dim3(256), 0, stream>>>(featb1, el1, er1, src, h1b, W2, Wr2,
                                                    feat2, res2);
  k_agg2<<<dim3(1024), dim3(128), 0, stream>>>(feat2, res2, src, al2, ar2, tc1w, tc1b, x1);
  k_final<<<dim3(4), dim3(1024), 0, stream>>>(x1, ln1g, ln1b, tc2w, tc2b, ln2g, ln2b, fcw, fcb, out);
}